// Round 10
// baseline (220.124 us; speedup 1.0000x reference)
//
#include <hip/hip_runtime.h>

#define DD 4096
#define HH 8192

enum Stage { S_X0 = 0, S_TANH, S_BIASOUT, S_PMUL, S_COPY, S_S2 };

typedef float vfloat4 __attribute__((ext_vector_type(4)));

__device__ inline unsigned short f2bf(float f) {
    unsigned int u = __float_as_uint(f);
    u += 0x7FFFu + ((u >> 16) & 1u);          // round-to-nearest-even
    return (unsigned short)(u >> 16);
}

// generic split-K prologue: build x[k0:k0+KS) in LDS
template <int STAGE, int KS, int SPREV, int KPREV>
__device__ inline void prologue(const float* __restrict__ Pprev,
                                const float* __restrict__ h, const float* __restrict__ c,
                                const float* __restrict__ b1, const float* __restrict__ b2,
                                float* __restrict__ s0g, float* __restrict__ t0g,
                                float* __restrict__ a1g, float* __restrict__ outv,
                                float* xs, float* part, int k0, int bx)
{
    constexpr int GROUPS = 256 / KS;
    const int tid = threadIdx.x;
    if constexpr (STAGE == S_X0) {
        if (tid < KS) {
            int k = k0 + tid;
            xs[tid] = (k < DD) ? h[k] : c[k - DD];
        }
    } else {
        const int g = tid / KS, j = tid % KS;
        float acc = 0.f;
        for (int s = g; s < SPREV; s += GROUPS)
            acc += Pprev[(size_t)s * KPREV + k0 + j];
        part[g * KS + j] = acc;
        __syncthreads();
        if (tid < KS) {
            const int k = k0 + tid;
            float tot = 0.f;
#pragma unroll
            for (int g2 = 0; g2 < GROUPS; ++g2) tot += part[g2 * KS + tid];
            float xv;
            if constexpr (STAGE == S_TANH) {
                float s = tanhf(tot + b1[k]);
                xv = s;
                if (bx == 0) { s0g[k] = s; t0g[k] = 1.f - s * s; }
            } else if constexpr (STAGE == S_BIASOUT) {
                xv = tot + b2[k];
                if (bx == 0) outv[k] = xv;
            } else if constexpr (STAGE == S_PMUL) {
                xv = t0g[k] * tot;
                if (bx == 0) a1g[k] = tot;
            } else if constexpr (STAGE == S_COPY) {
                xv = tot;
            } else { // S_S2
                float a1v = a1g[k];
                xv = t0g[k] * (tot - s0g[k] * a1v * a1v);
            }
            xs[tid] = xv;
        }
    }
    __syncthreads();
}

// fp32 GEMV phase (P1, P2): NT fp32 weight stream (single-use), fused bf16 conversion
// for rows k0 < CONVROWS into Wb.
template <int STAGE, int KS, int SPREV, int KPREV, int NTOT, int CONVROWS>
__global__ __launch_bounds__(256) void gemv_f32(
    const float* __restrict__ W, const float* __restrict__ Pprev,
    float* __restrict__ Pout, unsigned short* __restrict__ Wb,
    const float* __restrict__ h, const float* __restrict__ c,
    const float* __restrict__ b1, const float* __restrict__ b2,
    float* __restrict__ s0g, float* __restrict__ t0g, float* __restrict__ a1g,
    float* __restrict__ outv)
{
    __shared__ float xs[KS];
    __shared__ float part[256];
    const int bx = blockIdx.x, by = blockIdx.y;
    const int k0 = by * KS;
    prologue<STAGE, KS, SPREV, KPREV>(Pprev, h, c, b1, b2, s0g, t0g, a1g, outv,
                                      xs, part, k0, bx);

    const int ncol = bx * 1024 + threadIdx.x * 4;
    const float* Wp = W + (size_t)k0 * NTOT + ncol;
    float* op = Pout + (size_t)by * NTOT + ncol;
    unsigned short* Wbp = Wb + (size_t)k0 * NTOT + ncol;
    const bool doConv = (k0 < CONVROWS);

    float ax = 0.f, ay = 0.f, az = 0.f, aw = 0.f;
#pragma unroll 8
    for (int k = 0; k < KS; ++k) {
        const float xv = xs[k];
        const float* row = Wp + (size_t)k * NTOT;
        vfloat4 w = __builtin_nontemporal_load(reinterpret_cast<const vfloat4*>(row));
        ax = fmaf(xv, w.x, ax);
        ay = fmaf(xv, w.y, ay);
        az = fmaf(xv, w.z, az);
        aw = fmaf(xv, w.w, aw);
        if (doConv) {
            ushort4 o;
            o.x = f2bf(w.x); o.y = f2bf(w.y); o.z = f2bf(w.z); o.w = f2bf(w.w);
            *reinterpret_cast<ushort4*>(Wbp + (size_t)k * NTOT) = o;
        }
    }
    *reinterpret_cast<float4*>(op) = make_float4(ax, ay, az, aw);
}

// bf16 GEMV phase (P3..P6): uint4 = 8 bf16/lane, weights L3-resident
template <int STAGE, int KS, int SPREV, int KPREV, int NTOT>
__global__ __launch_bounds__(256) void gemv_b16(
    const unsigned short* __restrict__ Wb, const float* __restrict__ Pprev,
    float* __restrict__ Pout,
    const float* __restrict__ h, const float* __restrict__ c,
    const float* __restrict__ b1, const float* __restrict__ b2,
    float* __restrict__ s0g, float* __restrict__ t0g, float* __restrict__ a1g,
    float* __restrict__ outv)
{
    __shared__ float xs[KS];
    __shared__ float part[256];
    const int bx = blockIdx.x, by = blockIdx.y;
    const int k0 = by * KS;
    prologue<STAGE, KS, SPREV, KPREV>(Pprev, h, c, b1, b2, s0g, t0g, a1g, outv,
                                      xs, part, k0, bx);

    const int ncol = bx * 2048 + threadIdx.x * 8;
    const unsigned short* Wp = Wb + (size_t)k0 * NTOT + ncol;
    float a0 = 0.f, a1 = 0.f, a2 = 0.f, a3 = 0.f;
    float a4 = 0.f, a5 = 0.f, a6 = 0.f, a7 = 0.f;
#pragma unroll 8
    for (int k = 0; k < KS; ++k) {
        const float xv = xs[k];
        const uint4 w = *reinterpret_cast<const uint4*>(Wp + (size_t)k * NTOT);
        a0 = fmaf(xv, __uint_as_float(w.x << 16), a0);
        a1 = fmaf(xv, __uint_as_float(w.x & 0xFFFF0000u), a1);
        a2 = fmaf(xv, __uint_as_float(w.y << 16), a2);
        a3 = fmaf(xv, __uint_as_float(w.y & 0xFFFF0000u), a3);
        a4 = fmaf(xv, __uint_as_float(w.z << 16), a4);
        a5 = fmaf(xv, __uint_as_float(w.z & 0xFFFF0000u), a5);
        a6 = fmaf(xv, __uint_as_float(w.w << 16), a6);
        a7 = fmaf(xv, __uint_as_float(w.w & 0xFFFF0000u), a7);
    }
    float* op = Pout + (size_t)by * NTOT + ncol;
    *reinterpret_cast<float4*>(op)     = make_float4(a0, a1, a2, a3);
    *reinterpret_cast<float4*>(op + 4) = make_float4(a4, a5, a6, a7);
}

// tail 1: partial[b] = sum over 256 cols of (sum_s P6[s][n])^2
template <int SPREV>
__global__ __launch_bounds__(256) void reduce_sq_partial(const float* __restrict__ P6,
                                                         float* __restrict__ partial) {
    const int n = blockIdx.x * 256 + threadIdx.x;
    float acc = 0.f;
#pragma unroll 8
    for (int s = 0; s < SPREV; ++s) acc += P6[(size_t)s * DD + n];
    float sq = acc * acc;
    for (int off = 32; off; off >>= 1) sq += __shfl_down(sq, off);
    __shared__ float ls[4];
    const int wid = threadIdx.x >> 6;
    if ((threadIdx.x & 63) == 0) ls[wid] = sq;
    __syncthreads();
    if (threadIdx.x == 0) partial[blockIdx.x] = ls[0] + ls[1] + ls[2] + ls[3];
}

// tail 2: out[DD] = sum(partial[0..15]) / DD
__global__ __launch_bounds__(64) void finalize_meansq(const float* __restrict__ partial,
                                                      float* __restrict__ dout) {
    float v = (threadIdx.x < 16) ? partial[threadIdx.x] : 0.f;
    for (int off = 8; off; off >>= 1) v += __shfl_down(v, off);
    if (threadIdx.x == 0) dout[DD] = v / (float)DD;
}

extern "C" void kernel_launch(void* const* d_in, const int* in_sizes, int n_in,
                              void* d_out, int out_size, void* d_ws, size_t ws_size,
                              hipStream_t stream) {
    const float* h  = (const float*)d_in[0];
    const float* c  = (const float*)d_in[3];
    const float* W1 = (const float*)d_in[4];   // (DD+CC) x HH row-major
    const float* b1 = (const float*)d_in[5];
    const float* W2 = (const float*)d_in[6];   // HH x DD row-major
    const float* b2 = (const float*)d_in[7];
    float* out = (float*)d_out;                // [0..4095]=dydt, [4096]=mean(drdt^2)
    float* ws = (float*)d_ws;

    // workspace (floats)
    float* P1 = ws;                 // 128 x 8192 (4 MB)
    float* P2 = P1 + 1048576;       // 256 x 4096 (4 MB)
    float* P3 = P2 + 1048576;       // 256 x 8192 (8 MB)
    float* P4 = P3 + 2097152;       // 512 x 4096 (8 MB)
    float* P5 = P4 + 2097152;       // 256 x 8192 (8 MB)
    float* P6 = P5 + 2097152;       // 512 x 4096 (8 MB)
    float* s0 = P6 + 2097152;       // 8192
    float* t0 = s0 + 8192;          // 8192
    float* a1 = t0 + 8192;          // 8192
    float* psum = a1 + 8192;        // 16
    unsigned short* W1b = (unsigned short*)(psum + 64);  // 4096 x 8192 bf16 (64 MB)
    unsigned short* W2b = W1b + (size_t)DD * HH;         // 8192 x 4096 bf16 (64 MB)

    // P1: a0 = concat(h,c) @ W1   K=8192 N=8192 grid(8,128) KS=64
    //     fp32 NT (single-use); convert top half -> W1b
    gemv_f32<S_X0, 64, 1, 1, HH, DD><<<dim3(8, 128), 256, 0, stream>>>(
        W1, nullptr, P1, W1b, h, c, b1, b2, s0, t0, a1, out);
    // P2: s0=tanh(a0+b1); F = s0 @ W2   K=8192 N=4096 grid(4,256) KS=32
    //     fp32 NT (single-use); convert all -> W2b
    gemv_f32<S_TANH, 32, 128, HH, DD, HH><<<dim3(4, 256), 256, 0, stream>>>(
        W2, P1, P2, W2b, h, c, b1, b2, s0, t0, a1, out);
    // P3: Ff=F+b2 -> out; a1 = Ff @ W1b   K=4096 N=8192 grid(4,256) KS=16 (bf16 L3)
    gemv_b16<S_BIASOUT, 16, 256, DD, HH><<<dim3(4, 256), 256, 0, stream>>>(
        W1b, P2, P3, h, c, b1, b2, s0, t0, a1, out);
    // P4: p1=t0*a1; v = p1 @ W2b   K=8192 N=4096 grid(2,512) KS=16 (bf16 L3)
    gemv_b16<S_PMUL, 16, 256, HH, DD><<<dim3(2, 512), 256, 0, stream>>>(
        W2b, P3, P4, h, c, b1, b2, s0, t0, a1, out);
    // P5: a2 = v @ W1b   K=4096 N=8192 grid(4,256) KS=16 (bf16 L3)
    gemv_b16<S_COPY, 16, 512, DD, HH><<<dim3(4, 256), 256, 0, stream>>>(
        W1b, P4, P5, h, c, b1, b2, s0, t0, a1, out);
    // P6: s2=t0*(a2-s0*a1^2); C2 = s2 @ W2b   K=8192 N=4096 grid(2,512) KS=16 (bf16 L3)
    gemv_b16<S_S2, 16, 256, HH, DD><<<dim3(2, 512), 256, 0, stream>>>(
        W2b, P5, P6, h, c, b1, b2, s0, t0, a1, out);
    // tails
    reduce_sq_partial<512><<<16, 256, 0, stream>>>(P6, psum);
    finalize_meansq<<<1, 64, 0, stream>>>(psum, out);
}

// Round 11
// 202.332 us; speedup vs baseline: 1.0879x; 1.0879x over previous
//
#include <hip/hip_runtime.h>

#define DD 4096
#define HH 8192

enum Stage { S_X0 = 0, S_TANH, S_BIASOUT, S_PMUL, S_COPY, S_S2 };

typedef float vfloat4 __attribute__((ext_vector_type(4)));

__device__ inline unsigned short f2bf(float f) {
    unsigned int u = __float_as_uint(f);
    u += 0x7FFFu + ((u >> 16) & 1u);          // round-to-nearest-even
    return (unsigned short)(u >> 16);
}

// fp32 streaming inner loop: 16B/lane; NT = evict-first; CONV = also write bf16 copy
template <bool NT, bool CONV, int KS, int NTOT>
__device__ inline void stream_f32(const float* __restrict__ Wp,
                                  const float* __restrict__ xs,
                                  float* __restrict__ op,
                                  unsigned short* __restrict__ Wbp) {
    float ax = 0.f, ay = 0.f, az = 0.f, aw = 0.f;
#pragma unroll 8
    for (int k = 0; k < KS; ++k) {
        const float xv = xs[k];
        const float* row = Wp + (size_t)k * NTOT;
        vfloat4 w;
        if constexpr (NT)
            w = __builtin_nontemporal_load(reinterpret_cast<const vfloat4*>(row));
        else
            w = *reinterpret_cast<const vfloat4*>(row);
        ax = fmaf(xv, w.x, ax);
        ay = fmaf(xv, w.y, ay);
        az = fmaf(xv, w.z, az);
        aw = fmaf(xv, w.w, aw);
        if constexpr (CONV) {
            ushort4 o;
            o.x = f2bf(w.x); o.y = f2bf(w.y); o.z = f2bf(w.z); o.w = f2bf(w.w);
            *reinterpret_cast<ushort4*>(Wbp + (size_t)k * NTOT) = o;
        }
    }
    *reinterpret_cast<float4*>(op) = make_float4(ax, ay, az, aw);
}

// generic split-K prologue: build x[k0:k0+KS) in LDS
template <int STAGE, int KS, int SPREV, int KPREV>
__device__ inline void prologue(const float* __restrict__ Pprev,
                                const float* __restrict__ h, const float* __restrict__ c,
                                const float* __restrict__ b1, const float* __restrict__ b2,
                                float* __restrict__ s0g, float* __restrict__ t0g,
                                float* __restrict__ a1g, float* __restrict__ outv,
                                float* xs, float* part, int k0, int bx)
{
    constexpr int GROUPS = 256 / KS;
    const int tid = threadIdx.x;
    if constexpr (STAGE == S_X0) {
        if (tid < KS) {
            int k = k0 + tid;
            xs[tid] = (k < DD) ? h[k] : c[k - DD];
        }
    } else {
        const int g = tid / KS, j = tid % KS;
        float acc = 0.f;
        for (int s = g; s < SPREV; s += GROUPS)
            acc += Pprev[(size_t)s * KPREV + k0 + j];
        part[g * KS + j] = acc;
        __syncthreads();
        if (tid < KS) {
            const int k = k0 + tid;
            float tot = 0.f;
#pragma unroll
            for (int g2 = 0; g2 < GROUPS; ++g2) tot += part[g2 * KS + tid];
            float xv;
            if constexpr (STAGE == S_TANH) {
                float s = tanhf(tot + b1[k]);
                xv = s;
                if (bx == 0) { s0g[k] = s; t0g[k] = 1.f - s * s; }
            } else if constexpr (STAGE == S_BIASOUT) {
                xv = tot + b2[k];
                if (bx == 0) outv[k] = xv;
            } else if constexpr (STAGE == S_PMUL) {
                xv = t0g[k] * tot;
                if (bx == 0) a1g[k] = tot;
            } else if constexpr (STAGE == S_COPY) {
                xv = tot;
            } else { // S_S2
                float a1v = a1g[k];
                xv = t0g[k] * (tot - s0g[k] * a1v * a1v);
            }
            xs[tid] = xv;
        }
    }
    __syncthreads();
}

// fp32 GEMV phase. NTMODE: 0=cached, 1=all NT, 2=NT for k0>=DD (+conv for k0<DD if CONV)
template <int STAGE, int KS, int SPREV, int KPREV, int NTOT, int NTMODE, bool CONV>
__global__ __launch_bounds__(256) void gemv_f32(
    const float* __restrict__ W, const float* __restrict__ Pprev,
    float* __restrict__ Pout, unsigned short* __restrict__ Wb,
    const float* __restrict__ h, const float* __restrict__ c,
    const float* __restrict__ b1, const float* __restrict__ b2,
    float* __restrict__ s0g, float* __restrict__ t0g, float* __restrict__ a1g,
    float* __restrict__ outv, unsigned* __restrict__ ctrz)
{
    __shared__ float xs[KS];
    __shared__ float part[256];
    const int bx = blockIdx.x, by = blockIdx.y;
    const int k0 = by * KS;
    prologue<STAGE, KS, SPREV, KPREV>(Pprev, h, c, b1, b2, s0g, t0g, a1g, outv,
                                      xs, part, k0, bx);

    // P6 also resets the tail kernel's arrival counter for this call
    if constexpr (STAGE == S_S2) {
        if (bx == 0 && by == 0 && threadIdx.x == 0) *ctrz = 0u;
    }

    const int ncol = bx * 1024 + threadIdx.x * 4;
    const float* Wp = W + (size_t)k0 * NTOT + ncol;
    float* op = Pout + (size_t)by * NTOT + ncol;
    unsigned short* Wbp = CONV ? (Wb + (size_t)k0 * NTOT + ncol) : nullptr;

    if constexpr (NTMODE == 0) {
        stream_f32<false, false, KS, NTOT>(Wp, xs, op, nullptr);
    } else if constexpr (NTMODE == 1) {
        stream_f32<true, false, KS, NTOT>(Wp, xs, op, nullptr);
    } else {
        if (k0 >= DD) stream_f32<true, false, KS, NTOT>(Wp, xs, op, nullptr);
        else          stream_f32<false, CONV, KS, NTOT>(Wp, xs, op, Wbp);
    }
}

// bf16 GEMV phase (P3, P5): 8 cols/thread via uint4 (16B/lane), weights L3-hot
template <int STAGE, int KS, int SPREV, int KPREV, int NTOT>
__global__ __launch_bounds__(256) void gemv_b16(
    const unsigned short* __restrict__ Wb, const float* __restrict__ Pprev,
    float* __restrict__ Pout,
    const float* __restrict__ h, const float* __restrict__ c,
    const float* __restrict__ b1, const float* __restrict__ b2,
    float* __restrict__ s0g, float* __restrict__ t0g, float* __restrict__ a1g,
    float* __restrict__ outv)
{
    __shared__ float xs[KS];
    __shared__ float part[256];
    const int bx = blockIdx.x, by = blockIdx.y;
    const int k0 = by * KS;
    prologue<STAGE, KS, SPREV, KPREV>(Pprev, h, c, b1, b2, s0g, t0g, a1g, outv,
                                      xs, part, k0, bx);

    const int ncol = bx * 2048 + threadIdx.x * 8;
    const unsigned short* Wp = Wb + (size_t)k0 * NTOT + ncol;
    float a0 = 0.f, a1 = 0.f, a2 = 0.f, a3 = 0.f;
    float a4 = 0.f, a5 = 0.f, a6 = 0.f, a7 = 0.f;
#pragma unroll 8
    for (int k = 0; k < KS; ++k) {
        const float xv = xs[k];
        const uint4 w = *reinterpret_cast<const uint4*>(Wp + (size_t)k * NTOT);
        a0 = fmaf(xv, __uint_as_float(w.x << 16), a0);
        a1 = fmaf(xv, __uint_as_float(w.x & 0xFFFF0000u), a1);
        a2 = fmaf(xv, __uint_as_float(w.y << 16), a2);
        a3 = fmaf(xv, __uint_as_float(w.y & 0xFFFF0000u), a3);
        a4 = fmaf(xv, __uint_as_float(w.z << 16), a4);
        a5 = fmaf(xv, __uint_as_float(w.z & 0xFFFF0000u), a5);
        a6 = fmaf(xv, __uint_as_float(w.w << 16), a6);
        a7 = fmaf(xv, __uint_as_float(w.w & 0xFFFF0000u), a7);
    }
    float* op = Pout + (size_t)by * NTOT + ncol;
    *reinterpret_cast<float4*>(op)     = make_float4(a0, a1, a2, a3);
    *reinterpret_cast<float4*>(op + 4) = make_float4(a4, a5, a6, a7);
}

// merged tail: 16 blocks; psum[b] = block partial of sum((reduced C2)^2);
// last-arriving block sums psum[0..15] in fixed order and writes out[DD].
template <int SPREV>
__global__ __launch_bounds__(256) void reduce_sq_final(const float* __restrict__ P6,
                                                       float* __restrict__ psum,
                                                       unsigned* __restrict__ ctr,
                                                       float* __restrict__ dout) {
    const int n = blockIdx.x * 256 + threadIdx.x;
    float acc = 0.f;
#pragma unroll 8
    for (int s = 0; s < SPREV; ++s) acc += P6[(size_t)s * DD + n];
    float sq = acc * acc;
    for (int off = 32; off; off >>= 1) sq += __shfl_down(sq, off);
    __shared__ float ls[4];
    const int wid = threadIdx.x >> 6;
    if ((threadIdx.x & 63) == 0) ls[wid] = sq;
    __syncthreads();
    if (threadIdx.x == 0) {
        psum[blockIdx.x] = ls[0] + ls[1] + ls[2] + ls[3];
        __threadfence();
        unsigned old = atomicAdd(ctr, 1u);
        if (old == 15u) {
            __threadfence();
            float t = 0.f;
#pragma unroll
            for (int i = 0; i < 16; ++i) t += psum[i];
            dout[DD] = t / (float)DD;
        }
    }
}

extern "C" void kernel_launch(void* const* d_in, const int* in_sizes, int n_in,
                              void* d_out, int out_size, void* d_ws, size_t ws_size,
                              hipStream_t stream) {
    const float* h  = (const float*)d_in[0];
    const float* c  = (const float*)d_in[3];
    const float* W1 = (const float*)d_in[4];   // (DD+CC) x HH row-major
    const float* b1 = (const float*)d_in[5];
    const float* W2 = (const float*)d_in[6];   // HH x DD row-major
    const float* b2 = (const float*)d_in[7];
    float* out = (float*)d_out;                // [0..4095]=dydt, [4096]=mean(drdt^2)
    float* ws = (float*)d_ws;

    // workspace (floats)
    float* P1 = ws;                 // 128 x 8192 (4 MB)
    float* P2 = P1 + 1048576;       // 256 x 4096 (4 MB)
    float* P3 = P2 + 1048576;       // 256 x 8192 (8 MB)
    float* P4 = P3 + 2097152;       // 256 x 4096 (4 MB)
    float* P5 = P4 + 1048576;       // 256 x 8192 (8 MB)
    float* P6 = P5 + 2097152;       // 256 x 4096 (4 MB)
    float* s0 = P6 + 1048576;       // 8192
    float* t0 = s0 + 8192;          // 8192
    float* a1 = t0 + 8192;          // 8192
    float* psum = a1 + 8192;        // 16 floats
    unsigned* ctr = (unsigned*)(psum + 16);              // arrival counter
    unsigned short* W1b = (unsigned short*)(psum + 64);  // 4096 x 8192 bf16 (64 MB)

    // P1: a0 = concat(h,c) @ W1   K=8192 N=8192 grid(8,128) KS=64
    //     top half cached + converted to W1b; bottom half NT (single use)
    gemv_f32<S_X0, 64, 1, 1, HH, 2, true><<<dim3(8, 128), 256, 0, stream>>>(
        W1, nullptr, P1, W1b, h, c, b1, b2, s0, t0, a1, out, nullptr);
    // P2: s0=tanh(a0+b1); F = s0 @ W2   K=8192 N=4096 grid(4,256) KS=32, cached
    gemv_f32<S_TANH, 32, 128, HH, DD, 0, false><<<dim3(4, 256), 256, 0, stream>>>(
        W2, P1, P2, nullptr, h, c, b1, b2, s0, t0, a1, out, nullptr);
    // P3: Ff=F+b2 -> out; a1 = Ff @ W1b   K=4096 N=8192 grid(4,256) KS=16 (bf16, L3)
    gemv_b16<S_BIASOUT, 16, 256, DD, HH><<<dim3(4, 256), 256, 0, stream>>>(
        W1b, P2, P3, h, c, b1, b2, s0, t0, a1, out);
    // P4: p1=t0*a1; v = p1 @ W2   K=8192 N=4096 grid(4,256) KS=32, cached (L3-hot)
    gemv_f32<S_PMUL, 32, 256, HH, DD, 0, false><<<dim3(4, 256), 256, 0, stream>>>(
        W2, P3, P4, nullptr, h, c, b1, b2, s0, t0, a1, out, nullptr);
    // P5: a2 = v @ W1b   K=4096 N=8192 grid(4,256) KS=16 (bf16, L3)
    gemv_b16<S_COPY, 16, 256, DD, HH><<<dim3(4, 256), 256, 0, stream>>>(
        W1b, P4, P5, h, c, b1, b2, s0, t0, a1, out);
    // P6: s2=t0*(a2-s0*a1^2); C2 = s2 @ W2   K=8192 N=4096 grid(4,256) KS=32, NT (last use)
    //     also zeroes the tail arrival counter
    gemv_f32<S_S2, 32, 256, HH, DD, 1, false><<<dim3(4, 256), 256, 0, stream>>>(
        W2, P5, P6, nullptr, h, c, b1, b2, s0, t0, a1, out, ctr);
    // merged tail: C2 reduce + square + mean -> out[DD]
    reduce_sq_final<256><<<16, 256, 0, stream>>>(P6, psum, ctr, out);
}